// Round 10
// baseline (231.731 us; speedup 1.0000x reference)
//
#include <hip/hip_runtime.h>
#include <hip/hip_bf16.h>
#include <math.h>

// Problem constants
#define SEQ   2048
#define HID   1024
#define NH    16
#define NKV   4
#define DH    64
#define GQ    (NH / NKV)
#define NQKV  1536          // fused QKV output width
#define KT    64            // attention key-tile
#define QB    32            // queries per block (2 q-frags per wave)
#define CH    512           // split-K chunk of keys (4 chunks; R7 proved 2 regresses)
#define NCH   (SEQ / CH)    // 4
#define PSTR  72            // Pst row stride (u16)
#define LNSC  0.2878231366f // ln(10000)/32
#define GS    528           // gemm LDS group stride: 8 rows x 64 u16 + 16 pad
#define BUFS  (8 * GS)      // one staging buffer = 8 groups
#define QSCALE 0.18033688011112042f  // 0.125 * log2(e): attn uses exp2

typedef __attribute__((ext_vector_type(8))) short bf16x8;
typedef __attribute__((ext_vector_type(4))) float f32x4;
typedef unsigned short u16;
typedef unsigned int u32;

__device__ __forceinline__ u16 f2bf(float f) {
    union { float f; unsigned u; } x; x.f = f;
    unsigned r = x.u + 0x7fffu + ((x.u >> 16) & 1u);   // RNE
    return (u16)(r >> 16);
}
// HW packed f32->bf16 (RNE), 1 VALU op instead of ~10
__device__ __forceinline__ u32 cvtpk(float lo, float hi) {
    u32 r;
    asm("v_cvt_pk_bf16_f32 %0, %1, %2" : "=v"(r) : "v"(lo), "v"(hi));
    return r;
}
// async global->LDS: per-lane global gather, LDS dest = wave-uniform base
// + lane*16B
__device__ __forceinline__ void load_lds16(const u16* g, u16* l) {
    __builtin_amdgcn_global_load_lds(
        (const __attribute__((address_space(1))) unsigned int*)g,
        (__attribute__((address_space(3))) unsigned int*)l, 16, 0, 0);
}

// ---------------------------------------------------------------------------
// Setup: weight transposes (z=0..3) + X fp32->bf16 convert (z=4), one launch.
// R10: z==4 block (0,0) also zeroes the split-K fixup counters (stream order
// guarantees they are zero before attn launches; workspace is poisoned by
// the harness so self-zeroing is mandatory).
// ---------------------------------------------------------------------------
__global__ __launch_bounds__(256) void setup(const float* __restrict__ X,
                                             const float* __restrict__ Wq,
                                             const float* __restrict__ Wk,
                                             const float* __restrict__ Wv,
                                             const float* __restrict__ Wo,
                                             u16* __restrict__ Xb,
                                             u16* __restrict__ Wt,
                                             u16* __restrict__ WoT,
                                             u32* __restrict__ cnt) {
    const int z = blockIdx.z;
    if (z == 4) {
        if (blockIdx.x == 0 && blockIdx.y == 0)
            cnt[threadIdx.x] = 0;   // 256 counters = (64 q-tiles) x NKV
        const int idx = ((int)blockIdx.y * 64 + (int)blockIdx.x) * 256 + threadIdx.x;
        const float4 v = ((const float4*)X)[idx];
        ushort4 o;
        o.x = f2bf(v.x); o.y = f2bf(v.y); o.z = f2bf(v.z); o.w = f2bf(v.w);
        ((ushort4*)Xb)[idx] = o;
        return;
    }
    const float* in; u16* out; int N;
    if (z == 0)      { in = Wq; out = Wt;                             N = HID; }
    else if (z == 1) { in = Wk; out = Wt + (size_t)HID * HID;         N = 256; }
    else if (z == 2) { in = Wv; out = Wt + (size_t)(HID + 256) * HID; N = 256; }
    else             { in = Wo; out = WoT;                            N = HID; }

    const int n0 = blockIdx.x * 32;
    if (n0 >= N) return;
    const int k0 = blockIdx.y * 32;

    __shared__ float t[32][33];
    const int tx = threadIdx.x & 31;
    const int ty = threadIdx.x >> 5;
    #pragma unroll
    for (int i = 0; i < 4; ++i)
        t[ty + i * 8][tx] = in[(size_t)(k0 + ty + i * 8) * N + n0 + tx];
    __syncthreads();
    #pragma unroll
    for (int i = 0; i < 4; ++i)
        out[(size_t)(n0 + ty + i * 8) * HID + k0 + tx] = f2bf(t[tx][ty + i * 8]);
}

// ---------------------------------------------------------------------------
// QKV GEMM, BM=64, BN=64, 4-buffer unroll-2 K-loop, XOR-swizzled B staging
// (R6 config, neutral vs R1 -- kept: strictly conflict-reducing).
// ---------------------------------------------------------------------------
__global__ __launch_bounds__(256, 3) void gemm_qkv(const u16* __restrict__ A,
                                                   const u16* __restrict__ Bt,
                                                   u16* __restrict__ Qb,
                                                   u16* __restrict__ Kb,
                                                   u16* __restrict__ VTg) {
    __shared__ u16 Bs[4 * BUFS];

    const int tid  = threadIdx.x;
    const int lane = tid & 63;
    const int w    = tid >> 6;
    const int c    = lane & 15;
    const int quad = lane >> 4;
    const int m0   = blockIdx.y * 64;
    const int n0   = blockIdx.x * 64;

    // staging: wave w owns groups 2w, 2w+1 (rows w*16..w*16+15)
    const int rr8 = lane >> 3;                 // row in 8-row group
    const int cc8 = lane & 7;                  // 16B chunk slot
    const u16* gB0 = Bt + (size_t)(n0 + w * 16 + rr8) * HID + ((cc8 ^ rr8) * 8);
    const u16* gB1 = gB0 + (size_t)8 * HID;
    const int  gofs0 = (w * 2) * GS, gofs1 = (w * 2 + 1) * GS;

    const u16* gA = A + (size_t)(m0 + w * 16 + c) * HID + quad * 8;
    // B-frag read: row (c&7) of group (c>>3), chunk (ks*4+quad) XOR row
    const int bbase = (c >> 3) * GS + (c & 7) * 64;
    int bsw[2];
    #pragma unroll
    for (int ks = 0; ks < 2; ++ks)
        bsw[ks] = bbase + (((ks * 4 + quad) ^ (c & 7)) * 8);

    f32x4 acc[4];
    #pragma unroll
    for (int nt = 0; nt < 4; ++nt) acc[nt] = (f32x4){0.f, 0.f, 0.f, 0.f};

    bf16x8 afc[2], afB[2], afn[2];
    afc[0] = *(const bf16x8*)gA;
    afc[1] = *(const bf16x8*)(gA + 32);
    // prologue: stage tiles 0,1 into bufs 0,1
    load_lds16(gB0,      &Bs[0 * BUFS + gofs0]);
    load_lds16(gB1,      &Bs[0 * BUFS + gofs1]);
    load_lds16(gB0 + 64, &Bs[1 * BUFS + gofs0]);
    load_lds16(gB1 + 64, &Bs[1 * BUFS + gofs1]);

    const int NI = HID / 128;   // 8 intervals, 2 K-tiles each
    for (int i = 0; i < NI; ++i) {
        const int t0 = 2 * i;
        __syncthreads();
        if (i + 1 < NI) {
            load_lds16(gB0 + (t0 + 2) * 64, &Bs[((t0 + 2) & 3) * BUFS + gofs0]);
            load_lds16(gB1 + (t0 + 2) * 64, &Bs[((t0 + 2) & 3) * BUFS + gofs1]);
            load_lds16(gB0 + (t0 + 3) * 64, &Bs[((t0 + 3) & 3) * BUFS + gofs0]);
            load_lds16(gB1 + (t0 + 3) * 64, &Bs[((t0 + 3) & 3) * BUFS + gofs1]);
        }
        afB[0] = *(const bf16x8*)(gA + (t0 + 1) * 64);
        afB[1] = *(const bf16x8*)(gA + (t0 + 1) * 64 + 32);
        if (i + 1 < NI) {
            afn[0] = *(const bf16x8*)(gA + (t0 + 2) * 64);
            afn[1] = *(const bf16x8*)(gA + (t0 + 2) * 64 + 32);
        }
        // half A: tile t0
        {
            const int b = (t0 & 3) * BUFS;
            bf16x8 bfr[4][2];
            #pragma unroll
            for (int nt = 0; nt < 4; ++nt)
                #pragma unroll
                for (int ks = 0; ks < 2; ++ks)
                    bfr[nt][ks] = *(const bf16x8*)&Bs[b + nt * (2 * GS) + bsw[ks]];
            #pragma unroll
            for (int ks = 0; ks < 2; ++ks)
                #pragma unroll
                for (int nt = 0; nt < 4; ++nt)
                    acc[nt] = __builtin_amdgcn_mfma_f32_16x16x32_bf16(afc[ks], bfr[nt][ks], acc[nt], 0, 0, 0);
        }
        // half B: tile t0+1
        {
            const int b = ((t0 + 1) & 3) * BUFS;
            bf16x8 bfr[4][2];
            #pragma unroll
            for (int nt = 0; nt < 4; ++nt)
                #pragma unroll
                for (int ks = 0; ks < 2; ++ks)
                    bfr[nt][ks] = *(const bf16x8*)&Bs[b + nt * (2 * GS) + bsw[ks]];
            #pragma unroll
            for (int ks = 0; ks < 2; ++ks)
                #pragma unroll
                for (int nt = 0; nt < 4; ++nt)
                    acc[nt] = __builtin_amdgcn_mfma_f32_16x16x32_bf16(afB[ks], bfr[nt][ks], acc[nt], 0, 0, 0);
        }
        afc[0] = afn[0];
        afc[1] = afn[1];
    }

    const int s0 = m0 + w * 16 + quad * 4;
    if (n0 < 1280) {
        const bool isQ = (n0 < 1024);
        #pragma unroll
        for (int nt = 0; nt < 4; ++nt) {
            const int d = nt * 16 + c;
            const float inv_freq = __expf(-(float)(d & 30) * LNSC);
            const float sgn = (d & 1) ? 1.f : -1.f;
            #pragma unroll
            for (int rg = 0; rg < 4; ++rg) {
                const float self = acc[nt][rg];
                const float partner = __shfl_xor(self, 1);
                float sn, cs;
                __sincosf((float)(s0 + rg) * inv_freq, &sn, &cs);
                float o = fmaf(partner, sgn * sn, self * cs);
                if (isQ) {
                    // scale folded for exp2-based softmax: 1/8 * log2(e)
                    Qb[(size_t)(s0 + rg) * HID + n0 + d] = f2bf(o * QSCALE);
                } else {
                    const int kh = (n0 - 1024) >> 6;
                    Kb[((size_t)kh * SEQ + s0 + rg) * DH + d] = f2bf(o);
                }
            }
        }
    } else {
        const int kh = (n0 - 1280) >> 6;
        #pragma unroll
        for (int nt = 0; nt < 4; ++nt) {
            const int d = nt * 16 + c;
            ushort4 o;
            o.x = f2bf(acc[nt][0]); o.y = f2bf(acc[nt][1]);
            o.z = f2bf(acc[nt][2]); o.w = f2bf(acc[nt][3]);
            *(ushort4*)&VTg[((size_t)kh * DH + d) * SEQ + s0] = o;
        }
    }
}

// ---------------------------------------------------------------------------
// Wo GEMM, same 4-buffer unroll-2 structure + XOR swizzle, fp32 C output.
// Grid (16, 32).
// ---------------------------------------------------------------------------
__global__ __launch_bounds__(256, 3) void gemm64(const u16* __restrict__ A,
                                                 const u16* __restrict__ Bt,
                                                 float* __restrict__ C,
                                                 int K, int ldc) {
    __shared__ u16 Bs[4 * BUFS];

    const int tid  = threadIdx.x;
    const int lane = tid & 63;
    const int w    = tid >> 6;
    const int c    = lane & 15;
    const int quad = lane >> 4;
    const int m0   = blockIdx.y * 64;
    const int n0   = blockIdx.x * 64;

    const int rr8 = lane >> 3;
    const int cc8 = lane & 7;
    const u16* gB0 = Bt + (size_t)(n0 + w * 16 + rr8) * K + ((cc8 ^ rr8) * 8);
    const u16* gB1 = gB0 + (size_t)8 * K;
    const int  gofs0 = (w * 2) * GS, gofs1 = (w * 2 + 1) * GS;

    const u16* gA = A + (size_t)(m0 + w * 16 + c) * K + quad * 8;
    const int bbase = (c >> 3) * GS + (c & 7) * 64;
    int bsw[2];
    #pragma unroll
    for (int ks = 0; ks < 2; ++ks)
        bsw[ks] = bbase + (((ks * 4 + quad) ^ (c & 7)) * 8);

    f32x4 acc[4];
    #pragma unroll
    for (int nt = 0; nt < 4; ++nt) acc[nt] = (f32x4){0.f, 0.f, 0.f, 0.f};

    bf16x8 afc[2], afB[2], afn[2];
    afc[0] = *(const bf16x8*)gA;
    afc[1] = *(const bf16x8*)(gA + 32);
    load_lds16(gB0,      &Bs[0 * BUFS + gofs0]);
    load_lds16(gB1,      &Bs[0 * BUFS + gofs1]);
    load_lds16(gB0 + 64, &Bs[1 * BUFS + gofs0]);
    load_lds16(gB1 + 64, &Bs[1 * BUFS + gofs1]);

    const int NI = K / 128;
    for (int i = 0; i < NI; ++i) {
        const int t0 = 2 * i;
        __syncthreads();
        if (i + 1 < NI) {
            load_lds16(gB0 + (t0 + 2) * 64, &Bs[((t0 + 2) & 3) * BUFS + gofs0]);
            load_lds16(gB1 + (t0 + 2) * 64, &Bs[((t0 + 2) & 3) * BUFS + gofs1]);
            load_lds16(gB0 + (t0 + 3) * 64, &Bs[((t0 + 3) & 3) * BUFS + gofs0]);
            load_lds16(gB1 + (t0 + 3) * 64, &Bs[((t0 + 3) & 3) * BUFS + gofs1]);
        }
        afB[0] = *(const bf16x8*)(gA + (t0 + 1) * 64);
        afB[1] = *(const bf16x8*)(gA + (t0 + 1) * 64 + 32);
        if (i + 1 < NI) {
            afn[0] = *(const bf16x8*)(gA + (t0 + 2) * 64);
            afn[1] = *(const bf16x8*)(gA + (t0 + 2) * 64 + 32);
        }
        {
            const int b = (t0 & 3) * BUFS;
            bf16x8 bfr[4][2];
            #pragma unroll
            for (int nt = 0; nt < 4; ++nt)
                #pragma unroll
                for (int ks = 0; ks < 2; ++ks)
                    bfr[nt][ks] = *(const bf16x8*)&Bs[b + nt * (2 * GS) + bsw[ks]];
            #pragma unroll
            for (int ks = 0; ks < 2; ++ks)
                #pragma unroll
                for (int nt = 0; nt < 4; ++nt)
                    acc[nt] = __builtin_amdgcn_mfma_f32_16x16x32_bf16(afc[ks], bfr[nt][ks], acc[nt], 0, 0, 0);
        }
        {
            const int b = ((t0 + 1) & 3) * BUFS;
            bf16x8 bfr[4][2];
            #pragma unroll
            for (int nt = 0; nt < 4; ++nt)
                #pragma unroll
                for (int ks = 0; ks < 2; ++ks)
                    bfr[nt][ks] = *(const bf16x8*)&Bs[b + nt * (2 * GS) + bsw[ks]];
            #pragma unroll
            for (int ks = 0; ks < 2; ++ks)
                #pragma unroll
                for (int nt = 0; nt < 4; ++nt)
                    acc[nt] = __builtin_amdgcn_mfma_f32_16x16x32_bf16(afB[ks], bfr[nt][ks], acc[nt], 0, 0, 0);
        }
        afc[0] = afn[0];
        afc[1] = afn[1];
    }

    #pragma unroll
    for (int nt = 0; nt < 4; ++nt)
        #pragma unroll
        for (int rg = 0; rg < 4; ++rg)
            C[(size_t)(m0 + w * 16 + quad * 4 + rg) * ldc + n0 + nt * 16 + c] = acc[nt][rg];
}

// ---------------------------------------------------------------------------
// MFMA flash attention (R5-exact core: LDS-staged, XOR-swizzled K AND V
// tiles -- R9 proved V-direct-global costs 15us). R10: split-K merge fused
// in via last-block fixup (CUTLASS pattern): multi-chunk blocks write
// partials, device fence, atomicAdd on cnt[qt*NKV+kh]; the last of nchunks
// blocks re-fences (acquire) and merges+normalizes its 32 rows x 4 heads
// into At. attn_reduce dispatch eliminated.
// Grid (SEQ/QB=64 reversed, NKV, NCH=4).
// ---------------------------------------------------------------------------
__global__ __launch_bounds__(256) void attn_kernel(const u16* __restrict__ Qb,
                                                   const u16* __restrict__ Kb,
                                                   const u16* __restrict__ VTg,
                                                   float* __restrict__ Opart,
                                                   float* __restrict__ lpart,
                                                   u16* __restrict__ At,
                                                   u32* __restrict__ cnt) {
    __shared__ u16 Ks[2][64 * 64];   // [buf][key][d]   swizzled 16B slots
    __shared__ u16 Vs[2][64 * 64];   // [buf][d][key]   swizzled 16B slots
    __shared__ u16 Pst[4][QB * PSTR];   // per-wave [q][key]
    __shared__ u32 ticket;

    const int tid  = threadIdx.x;
    const int lane = tid & 63;
    const int w    = tid >> 6;
    const int c    = lane & 15;
    const int quad = lane >> 4;
    const int kh   = blockIdx.y;
    const int z    = blockIdx.z;
    const int qt   = (SEQ / QB - 1) - (int)blockIdx.x;   // heavy first
    const int q0   = qt * QB;
    const int h    = kh * GQ + w;

    const int kstart = z * CH;
    const int klim   = q0 + QB;
    if (kstart >= klim) return;                 // empty chunk
    const int kend   = (klim < kstart + CH) ? klim : (kstart + CH);
    const int ntiles = (kend - kstart + KT - 1) / KT;

    bf16x8 qf[2][2];
    #pragma unroll
    for (int g = 0; g < 2; ++g)
        #pragma unroll
        for (int ks = 0; ks < 2; ++ks)
            qf[g][ks] = *(const bf16x8*)&Qb[(size_t)(q0 + g * 16 + c) * HID + h * DH + ks * 32 + quad * 8];

    f32x4 accO[4][2];
    #pragma unroll
    for (int nt = 0; nt < 4; ++nt)
        #pragma unroll
        for (int g = 0; g < 2; ++g)
            accO[nt][g] = (f32x4){0.f, 0.f, 0.f, 0.f};
    float l[2] = {0.f, 0.f};

    // staging geometry: wave w stages rows [w*16, w*16+16) of both tiles.
    const int rr = lane >> 3;                    // 0..7
    const int sw = ((lane & 7) ^ rr) * 8;        // pre-swizzled chunk (u16)

    #pragma unroll
    for (int gi = 0; gi < 2; ++gi) {
        const int row = w * 16 + gi * 8;
        load_lds16(Kb + ((size_t)kh * SEQ + kstart + row + rr) * DH + sw,
                   &Ks[0][row * 64]);
        load_lds16(VTg + ((size_t)kh * DH + row + rr) * SEQ + kstart + sw,
                   &Vs[0][row * 64]);
    }

    for (int t = 0; t < ntiles; ++t) {
        const int kt0 = kstart + t * KT;
        __syncthreads();
        if (t + 1 < ntiles) {
            const int nk = kt0 + KT;
            const int nb = (t + 1) & 1;
            #pragma unroll
            for (int gi = 0; gi < 2; ++gi) {
                const int row = w * 16 + gi * 8;
                load_lds16(Kb + ((size_t)kh * SEQ + nk + row + rr) * DH + sw,
                           &Ks[nb][row * 64]);
                load_lds16(VTg + ((size_t)kh * DH + row + rr) * SEQ + nk + sw,
                           &Vs[nb][row * 64]);
            }
        }
        const int b = t & 1;

        f32x4 accS[4][2];
        #pragma unroll
        for (int nS = 0; nS < 4; ++nS)
            #pragma unroll
            for (int g = 0; g < 2; ++g)
                accS[nS][g] = (f32x4){0.f, 0.f, 0.f, 0.f};
        #pragma unroll
        for (int nS = 0; nS < 4; ++nS)
            #pragma unroll
            for (int ks = 0; ks < 2; ++ks) {
                const bf16x8 kf = *(const bf16x8*)
                    &Ks[b][(nS * 16 + c) * 64 + (((ks * 4 + quad) ^ (c & 7)) * 8)];
                #pragma unroll
                for (int g = 0; g < 2; ++g)
                    accS[nS][g] = __builtin_amdgcn_mfma_f32_16x16x32_bf16(kf, qf[g][ks], accS[nS][g], 0, 0, 0);
            }

        #pragma unroll
        for (int g = 0; g < 2; ++g) {
            const int q = q0 + g * 16 + c;
            // wave-uniform: tile entirely at-or-below diagonal for group g?
            const bool full = (kt0 + KT - 1 <= q0 + g * 16);
            #pragma unroll
            for (int nS = 0; nS < 4; ++nS) {
                const int key = kt0 + nS * 16 + quad * 4;
                float p0, p1, p2, p3;
                if (full) {
                    p0 = __builtin_amdgcn_exp2f(accS[nS][g][0]);
                    p1 = __builtin_amdgcn_exp2f(accS[nS][g][1]);
                    p2 = __builtin_amdgcn_exp2f(accS[nS][g][2]);
                    p3 = __builtin_amdgcn_exp2f(accS[nS][g][3]);
                } else {
                    p0 = (key + 0 <= q) ? __builtin_amdgcn_exp2f(accS[nS][g][0]) : 0.f;
                    p1 = (key + 1 <= q) ? __builtin_amdgcn_exp2f(accS[nS][g][1]) : 0.f;
                    p2 = (key + 2 <= q) ? __builtin_amdgcn_exp2f(accS[nS][g][2]) : 0.f;
                    p3 = (key + 3 <= q) ? __builtin_amdgcn_exp2f(accS[nS][g][3]) : 0.f;
                }
                l[g] += (p0 + p1) + (p2 + p3);
                u32* dst = (u32*)&Pst[w][(g * 16 + c) * PSTR + nS * 16 + quad * 4];
                dst[0] = cvtpk(p0, p1);
                dst[1] = cvtpk(p2, p3);
            }
        }
        __threadfence_block();

        #pragma unroll
        for (int ks2 = 0; ks2 < 2; ++ks2) {
            bf16x8 pf[2];
            #pragma unroll
            for (int g = 0; g < 2; ++g)
                pf[g] = *(const bf16x8*)&Pst[w][(g * 16 + c) * PSTR + ks2 * 32 + quad * 8];
            #pragma unroll
            for (int nt = 0; nt < 4; ++nt) {
                const bf16x8 vf = *(const bf16x8*)
                    &Vs[b][(nt * 16 + c) * 64 + (((ks2 * 4 + quad) ^ (c & 7)) * 8)];
                #pragma unroll
                for (int g = 0; g < 2; ++g)
                    accO[nt][g] = __builtin_amdgcn_mfma_f32_16x16x32_bf16(vf, pf[g], accO[nt][g], 0, 0, 0);
            }
        }
    }

    const int nchunks = (q0 + QB + CH - 1) / CH;

    if (nchunks == 1) {
        // single-chunk q-tile: write normalized At directly (own data only)
        #pragma unroll
        for (int g = 0; g < 2; ++g) {
            float lg = l[g];
            lg += __shfl_xor(lg, 16);
            lg += __shfl_xor(lg, 32);
            const float inv = 1.0f / lg;
            u16* Ap = At + (size_t)(q0 + g * 16 + c) * HID + h * DH;
            #pragma unroll
            for (int nt = 0; nt < 4; ++nt) {
                ushort4 o;
                o.x = f2bf(accO[nt][g][0] * inv);
                o.y = f2bf(accO[nt][g][1] * inv);
                o.z = f2bf(accO[nt][g][2] * inv);
                o.w = f2bf(accO[nt][g][3] * inv);
                *(ushort4*)&Ap[nt * 16 + quad * 4] = o;
            }
        }
        return;
    }

    // multi-chunk: write partials, then last-arriving block merges.
    #pragma unroll
    for (int g = 0; g < 2; ++g) {
        float lg = l[g];
        lg += __shfl_xor(lg, 16);
        lg += __shfl_xor(lg, 32);
        if (quad == 0)
            lpart[((size_t)z * SEQ + q0 + g * 16 + c) * NH + h] = lg;

        float* Op = Opart + ((size_t)z * SEQ + q0 + g * 16 + c) * HID + h * DH;
        #pragma unroll
        for (int nt = 0; nt < 4; ++nt)
            *(f32x4*)&Op[nt * 16 + quad * 4] = accO[nt][g];
    }

    // release: make this block's partials visible device-wide (cross-XCD)
    __threadfence();
    __syncthreads();
    if (tid == 0) ticket = atomicAdd(&cnt[qt * NKV + kh], 1u);
    __syncthreads();
    if (ticket != (u32)(nchunks - 1)) return;
    __threadfence();   // acquire: see all other chunks' partials

    // merge rows q0..q0+31, cols kh*256..kh*256+255 (heads kh*4..kh*4+3)
    const int mrow = q0 + (tid >> 3);
    const int colbase = kh * (GQ * DH);            // 256-col region
    #pragma unroll
    for (int it = 0; it < 8; ++it) {
        const int f4 = (tid & 7) + it * 8;         // 0..63 float4 slots
        const int mh = kh * GQ + (f4 >> 4);        // head for this slot
        float4 o = {0.f, 0.f, 0.f, 0.f};
        float lsum = 0.f;
        for (int zz = 0; zz < nchunks; ++zz) {
            const float4 o1 = *(const float4*)
                &Opart[((size_t)zz * SEQ + mrow) * HID + colbase + f4 * 4];
            o.x += o1.x; o.y += o1.y; o.z += o1.z; o.w += o1.w;
            lsum += lpart[((size_t)zz * SEQ + mrow) * NH + mh];
        }
        const float inv = 1.0f / lsum;
        ushort4 r;
        r.x = f2bf(o.x * inv); r.y = f2bf(o.y * inv);
        r.z = f2bf(o.z * inv); r.w = f2bf(o.w * inv);
        *(ushort4*)&At[(size_t)mrow * HID + colbase + f4 * 4] = r;
    }
}

// ---------------------------------------------------------------------------
extern "C" void kernel_launch(void* const* d_in, const int* in_sizes, int n_in,
                              void* d_out, int out_size, void* d_ws, size_t ws_size,
                              hipStream_t stream) {
    const float* X  = (const float*)d_in[0];
    const float* Wq = (const float*)d_in[1];
    const float* Wk = (const float*)d_in[2];
    const float* Wv = (const float*)d_in[3];
    const float* Wo = (const float*)d_in[4];
    float* out = (float*)d_out;

    // workspace layout
    u16* Wt     = (u16*)d_ws;                        // 1536 x 1024 bf16
    u16* WoT    = Wt + (size_t)NQKV * HID;           // 1024 x 1024
    u16* Xb     = WoT + (size_t)HID * HID;           // 2048 x 1024
    u16* At     = Xb + (size_t)SEQ * HID;            // 2048 x 1024
    u16* Qb     = At + (size_t)SEQ * HID;            // 2048 x 1024
    u16* Kb     = Qb + (size_t)SEQ * HID;            // 4 x 2048 x 64
    u16* VTg    = Kb + (size_t)NKV * SEQ * DH;       // 4 x 64 x 2048
    float* Opart = (float*)(VTg + (size_t)NKV * DH * SEQ);  // NCH x 2048 x 1024 f32
    float* lpart = Opart + (size_t)NCH * SEQ * HID;  // NCH x 2048 x 16 f32
    u32*   cnt   = (u32*)(lpart + (size_t)NCH * SEQ * NH);  // 256 u32

    dim3 blk(256);

    setup<<<dim3(64, 32, 5), blk, 0, stream>>>(X, Wq, Wk, Wv, Wo, Xb, Wt, WoT, cnt);

    gemm_qkv<<<dim3(NQKV / 64, SEQ / 64), blk, 0, stream>>>(Xb, Wt, Qb, Kb, VTg);

    attn_kernel<<<dim3(SEQ / QB, NKV, NCH), blk, 0, stream>>>(Qb, Kb, VTg, Opart, lpart, At, cnt);

    gemm64<<<dim3(HID / 64, SEQ / 64), blk, 0, stream>>>(At, WoT, out, HID, HID);
}

// Round 11
// 131.066 us; speedup vs baseline: 1.7680x; 1.7680x over previous
//
#include <hip/hip_runtime.h>
#include <hip/hip_bf16.h>
#include <math.h>

// Problem constants
#define SEQ   2048
#define HID   1024
#define NH    16
#define NKV   4
#define DH    64
#define GQ    (NH / NKV)
#define NQKV  1536          // fused QKV output width
#define KT    64            // attention key-tile
#define QB    32            // queries per block (2 q-frags per wave)
#define CH    512           // split-K chunk of keys (4 chunks)
#define NCH   (SEQ / CH)    // 4
#define PSTR  72            // Pst row stride (u16)
#define LNSC  0.2878231366f // ln(10000)/32
#define GS    528           // gemm LDS group stride: 8 rows x 64 u16 + 16 pad
#define BUFS  (8 * GS)      // one staging buffer = 8 groups
#define QSCALE 0.18033688011112042f  // 0.125 * log2(e): attn uses exp2

typedef __attribute__((ext_vector_type(8))) short bf16x8;
typedef __attribute__((ext_vector_type(4))) float f32x4;
typedef unsigned short u16;
typedef unsigned int u32;

__device__ __forceinline__ u16 f2bf(float f) {
    union { float f; unsigned u; } x; x.f = f;
    unsigned r = x.u + 0x7fffu + ((x.u >> 16) & 1u);   // RNE
    return (u16)(r >> 16);
}
// HW packed f32->bf16 (RNE), 1 VALU op instead of ~10
__device__ __forceinline__ u32 cvtpk(float lo, float hi) {
    u32 r;
    asm("v_cvt_pk_bf16_f32 %0, %1, %2" : "=v"(r) : "v"(lo), "v"(hi));
    return r;
}
// async global->LDS: per-lane global gather, LDS dest = wave-uniform base
// + lane*16B
__device__ __forceinline__ void load_lds16(const u16* g, u16* l) {
    __builtin_amdgcn_global_load_lds(
        (const __attribute__((address_space(1))) unsigned int*)g,
        (__attribute__((address_space(3))) unsigned int*)l, 16, 0, 0);
}

// ---------------------------------------------------------------------------
// Setup: weight transposes (z=0..3) + X fp32->bf16 convert (z=4), one launch.
// ---------------------------------------------------------------------------
__global__ __launch_bounds__(256) void setup(const float* __restrict__ X,
                                             const float* __restrict__ Wq,
                                             const float* __restrict__ Wk,
                                             const float* __restrict__ Wv,
                                             const float* __restrict__ Wo,
                                             u16* __restrict__ Xb,
                                             u16* __restrict__ Wt,
                                             u16* __restrict__ WoT) {
    const int z = blockIdx.z;
    if (z == 4) {
        const int idx = ((int)blockIdx.y * 64 + (int)blockIdx.x) * 256 + threadIdx.x;
        const float4 v = ((const float4*)X)[idx];
        ushort4 o;
        o.x = f2bf(v.x); o.y = f2bf(v.y); o.z = f2bf(v.z); o.w = f2bf(v.w);
        ((ushort4*)Xb)[idx] = o;
        return;
    }
    const float* in; u16* out; int N;
    if (z == 0)      { in = Wq; out = Wt;                             N = HID; }
    else if (z == 1) { in = Wk; out = Wt + (size_t)HID * HID;         N = 256; }
    else if (z == 2) { in = Wv; out = Wt + (size_t)(HID + 256) * HID; N = 256; }
    else             { in = Wo; out = WoT;                            N = HID; }

    const int n0 = blockIdx.x * 32;
    if (n0 >= N) return;
    const int k0 = blockIdx.y * 32;

    __shared__ float t[32][33];
    const int tx = threadIdx.x & 31;
    const int ty = threadIdx.x >> 5;
    #pragma unroll
    for (int i = 0; i < 4; ++i)
        t[ty + i * 8][tx] = in[(size_t)(k0 + ty + i * 8) * N + n0 + tx];
    __syncthreads();
    #pragma unroll
    for (int i = 0; i < 4; ++i)
        out[(size_t)(n0 + ty + i * 8) * HID + k0 + tx] = f2bf(t[tx][ty + i * 8]);
}

// ---------------------------------------------------------------------------
// QKV GEMM, BM=64, BN=64. 4-buffer unroll-2 K-loop (R5-exact, best verified
// at 131.36us): per barrier interval stage tiles t+2,t+3 and compute t,t+1.
// Grid (24, 32); launch_bounds(256,3).
// ---------------------------------------------------------------------------
__global__ __launch_bounds__(256, 3) void gemm_qkv(const u16* __restrict__ A,
                                                   const u16* __restrict__ Bt,
                                                   u16* __restrict__ Qb,
                                                   u16* __restrict__ Kb,
                                                   u16* __restrict__ VTg) {
    __shared__ u16 Bs[4 * BUFS];

    const int tid  = threadIdx.x;
    const int lane = tid & 63;
    const int w    = tid >> 6;
    const int c    = lane & 15;
    const int quad = lane >> 4;
    const int m0   = blockIdx.y * 64;
    const int n0   = blockIdx.x * 64;

    // staging: wave w owns groups 2w, 2w+1 (rows w*16..w*16+15)
    const u16* gB0 = Bt + (size_t)(n0 + w * 16 + (lane >> 3)) * HID + (lane & 7) * 8;
    const u16* gB1 = gB0 + (size_t)8 * HID;
    const int  gofs0 = (w * 2) * GS, gofs1 = (w * 2 + 1) * GS;

    const u16* gA = A + (size_t)(m0 + w * 16 + c) * HID + quad * 8;
    const int  bfoff = (c >> 3) * GS + (c & 7) * 64 + quad * 8;

    f32x4 acc[4];
    #pragma unroll
    for (int nt = 0; nt < 4; ++nt) acc[nt] = (f32x4){0.f, 0.f, 0.f, 0.f};

    bf16x8 afc[2], afB[2], afn[2];
    afc[0] = *(const bf16x8*)gA;
    afc[1] = *(const bf16x8*)(gA + 32);
    // prologue: stage tiles 0,1 into bufs 0,1
    load_lds16(gB0,      &Bs[0 * BUFS + gofs0]);
    load_lds16(gB1,      &Bs[0 * BUFS + gofs1]);
    load_lds16(gB0 + 64, &Bs[1 * BUFS + gofs0]);
    load_lds16(gB1 + 64, &Bs[1 * BUFS + gofs1]);

    const int NI = HID / 128;   // 8 intervals, 2 K-tiles each
    for (int i = 0; i < NI; ++i) {
        const int t0 = 2 * i;
        __syncthreads();
        if (i + 1 < NI) {
            load_lds16(gB0 + (t0 + 2) * 64, &Bs[((t0 + 2) & 3) * BUFS + gofs0]);
            load_lds16(gB1 + (t0 + 2) * 64, &Bs[((t0 + 2) & 3) * BUFS + gofs1]);
            load_lds16(gB0 + (t0 + 3) * 64, &Bs[((t0 + 3) & 3) * BUFS + gofs0]);
            load_lds16(gB1 + (t0 + 3) * 64, &Bs[((t0 + 3) & 3) * BUFS + gofs1]);
        }
        afB[0] = *(const bf16x8*)(gA + (t0 + 1) * 64);
        afB[1] = *(const bf16x8*)(gA + (t0 + 1) * 64 + 32);
        if (i + 1 < NI) {
            afn[0] = *(const bf16x8*)(gA + (t0 + 2) * 64);
            afn[1] = *(const bf16x8*)(gA + (t0 + 2) * 64 + 32);
        }
        // half A: tile t0
        {
            const int b = (t0 & 3) * BUFS;
            bf16x8 bfr[4][2];
            #pragma unroll
            for (int nt = 0; nt < 4; ++nt)
                #pragma unroll
                for (int ks = 0; ks < 2; ++ks)
                    bfr[nt][ks] = *(const bf16x8*)&Bs[b + nt * (2 * GS) + ks * 32 + bfoff];
            #pragma unroll
            for (int ks = 0; ks < 2; ++ks)
                #pragma unroll
                for (int nt = 0; nt < 4; ++nt)
                    acc[nt] = __builtin_amdgcn_mfma_f32_16x16x32_bf16(afc[ks], bfr[nt][ks], acc[nt], 0, 0, 0);
        }
        // half B: tile t0+1
        {
            const int b = ((t0 + 1) & 3) * BUFS;
            bf16x8 bfr[4][2];
            #pragma unroll
            for (int nt = 0; nt < 4; ++nt)
                #pragma unroll
                for (int ks = 0; ks < 2; ++ks)
                    bfr[nt][ks] = *(const bf16x8*)&Bs[b + nt * (2 * GS) + ks * 32 + bfoff];
            #pragma unroll
            for (int ks = 0; ks < 2; ++ks)
                #pragma unroll
                for (int nt = 0; nt < 4; ++nt)
                    acc[nt] = __builtin_amdgcn_mfma_f32_16x16x32_bf16(afB[ks], bfr[nt][ks], acc[nt], 0, 0, 0);
        }
        afc[0] = afn[0];
        afc[1] = afn[1];
    }

    const int s0 = m0 + w * 16 + quad * 4;
    if (n0 < 1280) {
        const bool isQ = (n0 < 1024);
        #pragma unroll
        for (int nt = 0; nt < 4; ++nt) {
            const int d = nt * 16 + c;
            const float inv_freq = __expf(-(float)(d & 30) * LNSC);
            const float sgn = (d & 1) ? 1.f : -1.f;
            #pragma unroll
            for (int rg = 0; rg < 4; ++rg) {
                const float self = acc[nt][rg];
                const float partner = __shfl_xor(self, 1);
                float sn, cs;
                __sincosf((float)(s0 + rg) * inv_freq, &sn, &cs);
                float o = fmaf(partner, sgn * sn, self * cs);
                if (isQ) {
                    // scale folded for exp2-based softmax: 1/8 * log2(e)
                    Qb[(size_t)(s0 + rg) * HID + n0 + d] = f2bf(o * QSCALE);
                } else {
                    const int kh = (n0 - 1024) >> 6;
                    Kb[((size_t)kh * SEQ + s0 + rg) * DH + d] = f2bf(o);
                }
            }
        }
    } else {
        const int kh = (n0 - 1280) >> 6;
        #pragma unroll
        for (int nt = 0; nt < 4; ++nt) {
            const int d = nt * 16 + c;
            ushort4 o;
            o.x = f2bf(acc[nt][0]); o.y = f2bf(acc[nt][1]);
            o.z = f2bf(acc[nt][2]); o.w = f2bf(acc[nt][3]);
            *(ushort4*)&VTg[((size_t)kh * DH + d) * SEQ + s0] = o;
        }
    }
}

// ---------------------------------------------------------------------------
// Wo GEMM, same 4-buffer unroll-2 structure, fp32 C output. Grid (16, 32).
// ---------------------------------------------------------------------------
__global__ __launch_bounds__(256, 3) void gemm64(const u16* __restrict__ A,
                                                 const u16* __restrict__ Bt,
                                                 float* __restrict__ C,
                                                 int K, int ldc) {
    __shared__ u16 Bs[4 * BUFS];

    const int tid  = threadIdx.x;
    const int lane = tid & 63;
    const int w    = tid >> 6;
    const int c    = lane & 15;
    const int quad = lane >> 4;
    const int m0   = blockIdx.y * 64;
    const int n0   = blockIdx.x * 64;

    const u16* gB0 = Bt + (size_t)(n0 + w * 16 + (lane >> 3)) * K + (lane & 7) * 8;
    const u16* gB1 = gB0 + (size_t)8 * K;
    const int  gofs0 = (w * 2) * GS, gofs1 = (w * 2 + 1) * GS;

    const u16* gA = A + (size_t)(m0 + w * 16 + c) * K + quad * 8;
    const int  bfoff = (c >> 3) * GS + (c & 7) * 64 + quad * 8;

    f32x4 acc[4];
    #pragma unroll
    for (int nt = 0; nt < 4; ++nt) acc[nt] = (f32x4){0.f, 0.f, 0.f, 0.f};

    bf16x8 afc[2], afB[2], afn[2];
    afc[0] = *(const bf16x8*)gA;
    afc[1] = *(const bf16x8*)(gA + 32);
    load_lds16(gB0,      &Bs[0 * BUFS + gofs0]);
    load_lds16(gB1,      &Bs[0 * BUFS + gofs1]);
    load_lds16(gB0 + 64, &Bs[1 * BUFS + gofs0]);
    load_lds16(gB1 + 64, &Bs[1 * BUFS + gofs1]);

    const int NI = K / 128;
    for (int i = 0; i < NI; ++i) {
        const int t0 = 2 * i;
        __syncthreads();
        if (i + 1 < NI) {
            load_lds16(gB0 + (t0 + 2) * 64, &Bs[((t0 + 2) & 3) * BUFS + gofs0]);
            load_lds16(gB1 + (t0 + 2) * 64, &Bs[((t0 + 2) & 3) * BUFS + gofs1]);
            load_lds16(gB0 + (t0 + 3) * 64, &Bs[((t0 + 3) & 3) * BUFS + gofs0]);
            load_lds16(gB1 + (t0 + 3) * 64, &Bs[((t0 + 3) & 3) * BUFS + gofs1]);
        }
        afB[0] = *(const bf16x8*)(gA + (t0 + 1) * 64);
        afB[1] = *(const bf16x8*)(gA + (t0 + 1) * 64 + 32);
        if (i + 1 < NI) {
            afn[0] = *(const bf16x8*)(gA + (t0 + 2) * 64);
            afn[1] = *(const bf16x8*)(gA + (t0 + 2) * 64 + 32);
        }
        {
            const int b = (t0 & 3) * BUFS;
            bf16x8 bfr[4][2];
            #pragma unroll
            for (int nt = 0; nt < 4; ++nt)
                #pragma unroll
                for (int ks = 0; ks < 2; ++ks)
                    bfr[nt][ks] = *(const bf16x8*)&Bs[b + nt * (2 * GS) + ks * 32 + bfoff];
            #pragma unroll
            for (int ks = 0; ks < 2; ++ks)
                #pragma unroll
                for (int nt = 0; nt < 4; ++nt)
                    acc[nt] = __builtin_amdgcn_mfma_f32_16x16x32_bf16(afc[ks], bfr[nt][ks], acc[nt], 0, 0, 0);
        }
        {
            const int b = ((t0 + 1) & 3) * BUFS;
            bf16x8 bfr[4][2];
            #pragma unroll
            for (int nt = 0; nt < 4; ++nt)
                #pragma unroll
                for (int ks = 0; ks < 2; ++ks)
                    bfr[nt][ks] = *(const bf16x8*)&Bs[b + nt * (2 * GS) + ks * 32 + bfoff];
            #pragma unroll
            for (int ks = 0; ks < 2; ++ks)
                #pragma unroll
                for (int nt = 0; nt < 4; ++nt)
                    acc[nt] = __builtin_amdgcn_mfma_f32_16x16x32_bf16(afB[ks], bfr[nt][ks], acc[nt], 0, 0, 0);
        }
        afc[0] = afn[0];
        afc[1] = afn[1];
    }

    #pragma unroll
    for (int nt = 0; nt < 4; ++nt)
        #pragma unroll
        for (int rg = 0; rg < 4; ++rg)
            C[(size_t)(m0 + w * 16 + quad * 4 + rg) * ldc + n0 + nt * 16 + c] = acc[nt][rg];
}

// ---------------------------------------------------------------------------
// MFMA flash attention (R1/R5-exact: LDS-staged, XOR-swizzled K/V tiles).
// Grid (SEQ/QB=64 reversed, NKV, NCH=4). All later attn variants measured
// worse: V-direct-global (R9, -15us), NCH=2 (R7, -6us), last-block fixup
// (R10, -100us: per-block device fences serialize the memory system).
// ---------------------------------------------------------------------------
__global__ __launch_bounds__(256) void attn_kernel(const u16* __restrict__ Qb,
                                                   const u16* __restrict__ Kb,
                                                   const u16* __restrict__ VTg,
                                                   float* __restrict__ Opart,
                                                   float* __restrict__ lpart,
                                                   u16* __restrict__ At) {
    __shared__ u16 Ks[2][64 * 64];   // [buf][key][d]   swizzled 16B slots
    __shared__ u16 Vs[2][64 * 64];   // [buf][d][key]   swizzled 16B slots
    __shared__ u16 Pst[4][QB * PSTR];   // per-wave [q][key]

    const int tid  = threadIdx.x;
    const int lane = tid & 63;
    const int w    = tid >> 6;
    const int c    = lane & 15;
    const int quad = lane >> 4;
    const int kh   = blockIdx.y;
    const int z    = blockIdx.z;
    const int qt   = (SEQ / QB - 1) - (int)blockIdx.x;   // heavy first
    const int q0   = qt * QB;
    const int h    = kh * GQ + w;

    const int kstart = z * CH;
    const int klim   = q0 + QB;
    if (kstart >= klim) return;                 // empty chunk
    const int kend   = (klim < kstart + CH) ? klim : (kstart + CH);
    const int ntiles = (kend - kstart + KT - 1) / KT;

    bf16x8 qf[2][2];
    #pragma unroll
    for (int g = 0; g < 2; ++g)
        #pragma unroll
        for (int ks = 0; ks < 2; ++ks)
            qf[g][ks] = *(const bf16x8*)&Qb[(size_t)(q0 + g * 16 + c) * HID + h * DH + ks * 32 + quad * 8];

    f32x4 accO[4][2];
    #pragma unroll
    for (int nt = 0; nt < 4; ++nt)
        #pragma unroll
        for (int g = 0; g < 2; ++g)
            accO[nt][g] = (f32x4){0.f, 0.f, 0.f, 0.f};
    float l[2] = {0.f, 0.f};

    // staging geometry: wave w stages rows [w*16, w*16+16) of both tiles.
    const int rr = lane >> 3;                    // 0..7
    const int sw = ((lane & 7) ^ rr) * 8;        // pre-swizzled chunk (u16)

    #pragma unroll
    for (int gi = 0; gi < 2; ++gi) {
        const int row = w * 16 + gi * 8;
        load_lds16(Kb + ((size_t)kh * SEQ + kstart + row + rr) * DH + sw,
                   &Ks[0][row * 64]);
        load_lds16(VTg + ((size_t)kh * DH + row + rr) * SEQ + kstart + sw,
                   &Vs[0][row * 64]);
    }

    for (int t = 0; t < ntiles; ++t) {
        const int kt0 = kstart + t * KT;
        __syncthreads();
        if (t + 1 < ntiles) {
            const int nk = kt0 + KT;
            const int nb = (t + 1) & 1;
            #pragma unroll
            for (int gi = 0; gi < 2; ++gi) {
                const int row = w * 16 + gi * 8;
                load_lds16(Kb + ((size_t)kh * SEQ + nk + row + rr) * DH + sw,
                           &Ks[nb][row * 64]);
                load_lds16(VTg + ((size_t)kh * DH + row + rr) * SEQ + nk + sw,
                           &Vs[nb][row * 64]);
            }
        }
        const int b = t & 1;

        f32x4 accS[4][2];
        #pragma unroll
        for (int nS = 0; nS < 4; ++nS)
            #pragma unroll
            for (int g = 0; g < 2; ++g)
                accS[nS][g] = (f32x4){0.f, 0.f, 0.f, 0.f};
        #pragma unroll
        for (int nS = 0; nS < 4; ++nS)
            #pragma unroll
            for (int ks = 0; ks < 2; ++ks) {
                const bf16x8 kf = *(const bf16x8*)
                    &Ks[b][(nS * 16 + c) * 64 + (((ks * 4 + quad) ^ (c & 7)) * 8)];
                #pragma unroll
                for (int g = 0; g < 2; ++g)
                    accS[nS][g] = __builtin_amdgcn_mfma_f32_16x16x32_bf16(kf, qf[g][ks], accS[nS][g], 0, 0, 0);
            }

        #pragma unroll
        for (int g = 0; g < 2; ++g) {
            const int q = q0 + g * 16 + c;
            // wave-uniform: tile entirely at-or-below diagonal for group g?
            const bool full = (kt0 + KT - 1 <= q0 + g * 16);
            #pragma unroll
            for (int nS = 0; nS < 4; ++nS) {
                const int key = kt0 + nS * 16 + quad * 4;
                float p0, p1, p2, p3;
                if (full) {
                    p0 = __builtin_amdgcn_exp2f(accS[nS][g][0]);
                    p1 = __builtin_amdgcn_exp2f(accS[nS][g][1]);
                    p2 = __builtin_amdgcn_exp2f(accS[nS][g][2]);
                    p3 = __builtin_amdgcn_exp2f(accS[nS][g][3]);
                } else {
                    p0 = (key + 0 <= q) ? __builtin_amdgcn_exp2f(accS[nS][g][0]) : 0.f;
                    p1 = (key + 1 <= q) ? __builtin_amdgcn_exp2f(accS[nS][g][1]) : 0.f;
                    p2 = (key + 2 <= q) ? __builtin_amdgcn_exp2f(accS[nS][g][2]) : 0.f;
                    p3 = (key + 3 <= q) ? __builtin_amdgcn_exp2f(accS[nS][g][3]) : 0.f;
                }
                l[g] += (p0 + p1) + (p2 + p3);
                u32* dst = (u32*)&Pst[w][(g * 16 + c) * PSTR + nS * 16 + quad * 4];
                dst[0] = cvtpk(p0, p1);
                dst[1] = cvtpk(p2, p3);
            }
        }
        __threadfence_block();

        #pragma unroll
        for (int ks2 = 0; ks2 < 2; ++ks2) {
            bf16x8 pf[2];
            #pragma unroll
            for (int g = 0; g < 2; ++g)
                pf[g] = *(const bf16x8*)&Pst[w][(g * 16 + c) * PSTR + ks2 * 32 + quad * 8];
            #pragma unroll
            for (int nt = 0; nt < 4; ++nt) {
                const bf16x8 vf = *(const bf16x8*)
                    &Vs[b][(nt * 16 + c) * 64 + (((ks2 * 4 + quad) ^ (c & 7)) * 8)];
                #pragma unroll
                for (int g = 0; g < 2; ++g)
                    accO[nt][g] = __builtin_amdgcn_mfma_f32_16x16x32_bf16(vf, pf[g], accO[nt][g], 0, 0, 0);
            }
        }
    }

    const int nchunks = (q0 + QB + CH - 1) / CH;

    if (nchunks == 1) {
        // single-chunk q-tile: write normalized At directly (own data only)
        #pragma unroll
        for (int g = 0; g < 2; ++g) {
            float lg = l[g];
            lg += __shfl_xor(lg, 16);
            lg += __shfl_xor(lg, 32);
            const float inv = 1.0f / lg;
            u16* Ap = At + (size_t)(q0 + g * 16 + c) * HID + h * DH;
            #pragma unroll
            for (int nt = 0; nt < 4; ++nt) {
                ushort4 o;
                o.x = f2bf(accO[nt][g][0] * inv);
                o.y = f2bf(accO[nt][g][1] * inv);
                o.z = f2bf(accO[nt][g][2] * inv);
                o.w = f2bf(accO[nt][g][3] * inv);
                *(ushort4*)&Ap[nt * 16 + quad * 4] = o;
            }
        }
        return;
    }

    #pragma unroll
    for (int g = 0; g < 2; ++g) {
        float lg = l[g];
        lg += __shfl_xor(lg, 16);
        lg += __shfl_xor(lg, 32);
        if (quad == 0)
            lpart[((size_t)z * SEQ + q0 + g * 16 + c) * NH + h] = lg;

        float* Op = Opart + ((size_t)z * SEQ + q0 + g * 16 + c) * HID + h * DH;
        #pragma unroll
        for (int nt = 0; nt < 4; ++nt)
            *(f32x4*)&Op[nt * 16 + quad * 4] = accO[nt][g];
    }
}

// ---------------------------------------------------------------------------
// Merge split-K partials for rows >= CH only (rows < CH were written
// directly by attn). Grid: (SEQ-CH)*HID/4/256 = 1536 blocks.
// ---------------------------------------------------------------------------
__global__ __launch_bounds__(256) void attn_reduce(const float* __restrict__ Opart,
                                                   const float* __restrict__ lpart,
                                                   u16* __restrict__ At) {
    const int idx = blockIdx.x * 256 + threadIdx.x + (CH * HID / 4);
    const int q  = idx >> 8;
    const int h  = (idx & 255) >> 4;
    const int klim = (q & ~(QB - 1)) + QB;
    float4 o = ((const float4*)Opart)[idx];
    float  l = lpart[q * NH + h];
    #pragma unroll
    for (int z = 1; z < NCH; ++z) {
        if (z * CH < klim) {
            const float4 o1 = ((const float4*)Opart)[idx + z * (SEQ * HID / 4)];
            o.x += o1.x; o.y += o1.y; o.z += o1.z; o.w += o1.w;
            l += lpart[(z * SEQ + q) * NH + h];
        }
    }
    const float inv = 1.0f / l;
    ushort4 r;
    r.x = f2bf(o.x * inv); r.y = f2bf(o.y * inv);
    r.z = f2bf(o.z * inv); r.w = f2bf(o.w * inv);
    ((ushort4*)At)[idx] = r;
}

// ---------------------------------------------------------------------------
extern "C" void kernel_launch(void* const* d_in, const int* in_sizes, int n_in,
                              void* d_out, int out_size, void* d_ws, size_t ws_size,
                              hipStream_t stream) {
    const float* X  = (const float*)d_in[0];
    const float* Wq = (const float*)d_in[1];
    const float* Wk = (const float*)d_in[2];
    const float* Wv = (const float*)d_in[3];
    const float* Wo = (const float*)d_in[4];
    float* out = (float*)d_out;

    // workspace layout
    u16* Wt     = (u16*)d_ws;                        // 1536 x 1024 bf16
    u16* WoT    = Wt + (size_t)NQKV * HID;           // 1024 x 1024
    u16* Xb     = WoT + (size_t)HID * HID;           // 2048 x 1024
    u16* At     = Xb + (size_t)SEQ * HID;            // 2048 x 1024
    u16* Qb     = At + (size_t)SEQ * HID;            // 2048 x 1024
    u16* Kb     = Qb + (size_t)SEQ * HID;            // 4 x 2048 x 64
    u16* VTg    = Kb + (size_t)NKV * SEQ * DH;       // 4 x 64 x 2048
    float* Opart = (float*)(VTg + (size_t)NKV * DH * SEQ);  // NCH x 2048 x 1024 f32
    float* lpart = Opart + (size_t)NCH * SEQ * HID;  // NCH x 2048 x 16 f32

    dim3 blk(256);

    setup<<<dim3(64, 32, 5), blk, 0, stream>>>(X, Wq, Wk, Wv, Wo, Xb, Wt, WoT);

    gemm_qkv<<<dim3(NQKV / 64, SEQ / 64), blk, 0, stream>>>(Xb, Wt, Qb, Kb, VTg);

    attn_kernel<<<dim3(SEQ / QB, NKV, NCH), blk, 0, stream>>>(Qb, Kb, VTg, Opart, lpart, At);

    attn_reduce<<<((SEQ - CH) * HID / 4) / 256, blk, 0, stream>>>(Opart, lpart, At);

    gemm64<<<dim3(HID / 64, SEQ / 64), blk, 0, stream>>>(At, WoT, out, HID, HID);
}